// Round 1
// baseline (813.600 us; speedup 1.0000x reference)
//
#include <hip/hip_runtime.h>
#include <math.h>

#define SEQ   2048
#define NH    16
#define DEP   64
#define HID   1024

// ---------------------------------------------------------------------------
// Tiled fp32 GEMM: C[M,N] = A[M,K] @ B[K,N] + bias[N]
// qkv_mode==1: scatter output into q/k/v [head][seq][dep] (split-heads fused).
// Block: 256 threads, 64x64 output tile, BK=16, 4x4 per thread.
// ---------------------------------------------------------------------------
__global__ __launch_bounds__(256)
void gemm64(const float* __restrict__ A, const float* __restrict__ B,
            const float* __restrict__ bias, float* __restrict__ C,
            int M, int N, int K, int qkv_mode,
            float* __restrict__ qd, float* __restrict__ kd, float* __restrict__ vd)
{
    __shared__ float As[16][68];   // [k][m], pad 68 keeps float4 alignment
    __shared__ float Bs[16][68];   // [k][n]
    const int t  = threadIdx.x;
    const int tx = t & 15;
    const int ty = t >> 4;
    const int m0 = blockIdx.y * 64;
    const int n0 = blockIdx.x * 64;
    const int ar = t >> 2;       // 0..63  (A row within tile)
    const int as = t & 3;        // 0..3   (A k-segment)
    float acc[4][4] = {{0.f, 0.f, 0.f, 0.f}};

    for (int k0 = 0; k0 < K; k0 += 16) {
        __syncthreads();
        float4 av = *(const float4*)&A[(size_t)(m0 + ar) * K + k0 + as * 4];
        As[as*4+0][ar] = av.x;
        As[as*4+1][ar] = av.y;
        As[as*4+2][ar] = av.z;
        As[as*4+3][ar] = av.w;
        *(float4*)&Bs[ty][tx*4] = *(const float4*)&B[(size_t)(k0 + ty) * N + n0 + tx*4];
        __syncthreads();
        #pragma unroll
        for (int kk = 0; kk < 16; kk++) {
            float4 a4 = *(const float4*)&As[kk][ty*4];
            float4 b4 = *(const float4*)&Bs[kk][tx*4];
            float aa[4] = {a4.x, a4.y, a4.z, a4.w};
            float bb[4] = {b4.x, b4.y, b4.z, b4.w};
            #pragma unroll
            for (int i = 0; i < 4; i++)
                #pragma unroll
                for (int j = 0; j < 4; j++)
                    acc[i][j] = fmaf(aa[i], bb[j], acc[i][j]);
        }
    }

    const float bb0 = bias[n0 + tx*4 + 0];
    const float bb1 = bias[n0 + tx*4 + 1];
    const float bb2 = bias[n0 + tx*4 + 2];
    const float bb3 = bias[n0 + tx*4 + 3];
    if (qkv_mode) {
        // whole 64-col tile maps to one (part, head): n0 multiple of 64
        const int part = n0 >> 10;          // 0:q 1:k 2:v
        const int h    = (n0 & 1023) >> 6;  // head
        float* dst = (part == 0) ? qd : ((part == 1) ? kd : vd);
        #pragma unroll
        for (int i = 0; i < 4; i++) {
            const int row = m0 + ty*4 + i;
            float4 o = make_float4(acc[i][0] + bb0, acc[i][1] + bb1,
                                   acc[i][2] + bb2, acc[i][3] + bb3);
            *(float4*)&dst[((size_t)h * SEQ + row) * DEP + tx*4] = o;
        }
    } else {
        #pragma unroll
        for (int i = 0; i < 4; i++) {
            const int row = m0 + ty*4 + i;
            float4 o = make_float4(acc[i][0] + bb0, acc[i][1] + bb1,
                                   acc[i][2] + bb2, acc[i][3] + bb3);
            *(float4*)&C[(size_t)row * N + n0 + tx*4] = o;
        }
    }
}

// ---------------------------------------------------------------------------
// Flash-style causal attention with Transformer-XL relative bias.
// rel[i,j] = q_i . E[S-1-(i-j)] for j<=i (skew identity); masked entries are
// exactly -10000 -> exp underflows to 0, so only causal tiles are processed.
// One block per (64-row q-tile, head). 256 threads (16x16), 4x4 scores/thread.
// LDS overlays keep footprint at 51 KB (3 blocks/CU):
//   Qs [d][i] | Ks [d][j] -> reused as Ps [i][j] | EV: E-half [32][132] -> Vs [j][d]
// ---------------------------------------------------------------------------
__global__ __launch_bounds__(256)
void attn_flash(const float* __restrict__ q, const float* __restrict__ kk_,
                const float* __restrict__ vv_, const float* __restrict__ E,
                float* __restrict__ ctx)
{
    __shared__ float Qs[64*68];
    __shared__ float Ks[64*68];
    __shared__ float EV[64*68];

    const int t  = threadIdx.x;
    const int tx = t & 15;
    const int ty = t >> 4;
    const int h  = blockIdx.y;
    const int i0 = blockIdx.x * 64;

    const float* qh = q   + (size_t)h * SEQ * DEP;
    const float* kh = kk_ + (size_t)h * SEQ * DEP;
    const float* vh = vv_ + (size_t)h * SEQ * DEP;
    const float* Eh = E   + (size_t)h * SEQ * DEP;

    // Q tile -> LDS transposed [d][i]
    for (int u = t; u < 64*16; u += 256) {
        const int r = u >> 4, sg = u & 15;
        float4 x = *(const float4*)&qh[(size_t)(i0 + r) * DEP + sg*4];
        Qs[(sg*4+0)*68 + r] = x.x;
        Qs[(sg*4+1)*68 + r] = x.y;
        Qs[(sg*4+2)*68 + r] = x.z;
        Qs[(sg*4+3)*68 + r] = x.w;
    }

    float m_i[4], l_i[4], acc[4][4];
    #pragma unroll
    for (int a = 0; a < 4; a++) {
        m_i[a] = -INFINITY; l_i[a] = 0.f;
        #pragma unroll
        for (int c = 0; c < 4; c++) acc[a][c] = 0.f;
    }

    // band row for (a,c): base3 + (3 + c - a), base3 in [0,120], max read 126
    const int base3 = 60 + tx*4 - ty*4;
    const int nkt   = i0 / 64 + 1;

    float s[4][4];

    auto score_half = [&](int dbase) {
        #pragma unroll 2
        for (int dd = 0; dd < 32; dd++) {
            const int d = dbase + dd;
            float4 q4 = *(const float4*)&Qs[d*68 + ty*4];
            float4 k4 = *(const float4*)&Ks[d*68 + tx*4];
            const float* er_ = &EV[dd*132];
            float e7[7];
            #pragma unroll
            for (int u2 = 0; u2 < 7; u2++) e7[u2] = er_[base3 + u2];
            float qa[4] = {q4.x, q4.y, q4.z, q4.w};
            float kb[4] = {k4.x, k4.y, k4.z, k4.w};
            #pragma unroll
            for (int a = 0; a < 4; a++)
                #pragma unroll
                for (int c = 0; c < 4; c++)
                    s[a][c] = fmaf(qa[a], kb[c] + e7[3 + c - a], s[a][c]);
        }
    };

    for (int kt = 0; kt < nkt; kt++) {
        const int j0 = kt * 64;
        const int m0 = SEQ - 64 - i0 + j0;   // E band start (clamped loads; OOB rows only feed masked entries)

        __syncthreads();   // previous iteration's Ps/Vs reads complete

        float4 vr[4];      // V tile prefetch (stored to LDS in acc phase)
        float4 er[4];      // E d-half1 prefetch
        // K tile -> Ks transposed [d][j]
        for (int u = t; u < 64*16; u += 256) {
            const int r = u >> 4, sg = u & 15;
            float4 x = *(const float4*)&kh[(size_t)(j0 + r) * DEP + sg*4];
            Ks[(sg*4+0)*68 + r] = x.x;
            Ks[(sg*4+1)*68 + r] = x.y;
            Ks[(sg*4+2)*68 + r] = x.z;
            Ks[(sg*4+3)*68 + r] = x.w;
        }
        // E half0 (d 0..31) -> EV [d][band]; prefetch half1 + V to registers
        #pragma unroll
        for (int p = 0; p < 4; p++) {
            const int u  = t + p * 256;       // 0..1023
            const int br = u >> 3, sg = u & 7;
            int mm = m0 + br;
            mm = mm < 0 ? 0 : (mm > SEQ-1 ? SEQ-1 : mm);
            float4 x = *(const float4*)&Eh[(size_t)mm * DEP + sg*4];
            EV[(sg*4+0)*132 + br] = x.x;
            EV[(sg*4+1)*132 + br] = x.y;
            EV[(sg*4+2)*132 + br] = x.z;
            EV[(sg*4+3)*132 + br] = x.w;
            er[p] = *(const float4*)&Eh[(size_t)mm * DEP + 32 + sg*4];
            const int vr_ = u >> 4, vsg = u & 15;
            vr[p] = *(const float4*)&vh[(size_t)(j0 + vr_) * DEP + vsg*4];
        }
        __syncthreads();

        #pragma unroll
        for (int a = 0; a < 4; a++)
            #pragma unroll
            for (int c = 0; c < 4; c++) s[a][c] = 0.f;

        score_half(0);
        __syncthreads();                       // half0 E reads done
        #pragma unroll
        for (int p = 0; p < 4; p++) {          // store E half1
            const int u  = t + p * 256;
            const int br = u >> 3, sg = u & 7;
            EV[(sg*4+0)*132 + br] = er[p].x;
            EV[(sg*4+1)*132 + br] = er[p].y;
            EV[(sg*4+2)*132 + br] = er[p].z;
            EV[(sg*4+3)*132 + br] = er[p].w;
        }
        __syncthreads();
        score_half(32);

        // scale + causal mask (masked = exactly -10000, matching reference)
        #pragma unroll
        for (int a = 0; a < 4; a++) {
            const int ii = i0 + ty*4 + a;
            #pragma unroll
            for (int c = 0; c < 4; c++) {
                const int jj = j0 + tx*4 + c;
                s[a][c] = (jj <= ii) ? s[a][c] * 0.125f : -10000.0f;
            }
        }
        // online softmax update (row = 16 tx-lanes of one wave)
        #pragma unroll
        for (int a = 0; a < 4; a++) {
            float mx = fmaxf(fmaxf(s[a][0], s[a][1]), fmaxf(s[a][2], s[a][3]));
            mx = fmaxf(mx, __shfl_xor(mx, 1));
            mx = fmaxf(mx, __shfl_xor(mx, 2));
            mx = fmaxf(mx, __shfl_xor(mx, 4));
            mx = fmaxf(mx, __shfl_xor(mx, 8));
            const float mnew = fmaxf(m_i[a], mx);
            const float al   = expf(m_i[a] - mnew);   // first tile: exp(-inf)=0
            m_i[a] = mnew;
            float ps = 0.f;
            #pragma unroll
            for (int c = 0; c < 4; c++) {
                const float p = expf(s[a][c] - mnew);
                s[a][c] = p; ps += p;
            }
            ps += __shfl_xor(ps, 1);
            ps += __shfl_xor(ps, 2);
            ps += __shfl_xor(ps, 4);
            ps += __shfl_xor(ps, 8);
            l_i[a] = l_i[a] * al + ps;
            #pragma unroll
            for (int c = 0; c < 4; c++) acc[a][c] *= al;
        }

        __syncthreads();   // score-phase Ks/EV reads complete
        // P -> Ks buffer ([i][j]); V -> EV ([j][d])
        #pragma unroll
        for (int a = 0; a < 4; a++)
            *(float4*)&Ks[(ty*4+a)*68 + tx*4] =
                make_float4(s[a][0], s[a][1], s[a][2], s[a][3]);
        #pragma unroll
        for (int p = 0; p < 4; p++) {
            const int u = t + p * 256;
            const int r = u >> 4, sg = u & 15;
            *(float4*)&EV[r*68 + sg*4] = vr[p];
        }
        __syncthreads();

        // acc += P @ V  (p reads broadcast within wave: 4 distinct addrs)
        #pragma unroll 2
        for (int j = 0; j < 64; j++) {
            const float p0 = Ks[(ty*4+0)*68 + j];
            const float p1 = Ks[(ty*4+1)*68 + j];
            const float p2 = Ks[(ty*4+2)*68 + j];
            const float p3 = Ks[(ty*4+3)*68 + j];
            float4 v4 = *(const float4*)&EV[j*68 + tx*4];
            acc[0][0] = fmaf(p0, v4.x, acc[0][0]);
            acc[0][1] = fmaf(p0, v4.y, acc[0][1]);
            acc[0][2] = fmaf(p0, v4.z, acc[0][2]);
            acc[0][3] = fmaf(p0, v4.w, acc[0][3]);
            acc[1][0] = fmaf(p1, v4.x, acc[1][0]);
            acc[1][1] = fmaf(p1, v4.y, acc[1][1]);
            acc[1][2] = fmaf(p1, v4.z, acc[1][2]);
            acc[1][3] = fmaf(p1, v4.w, acc[1][3]);
            acc[2][0] = fmaf(p2, v4.x, acc[2][0]);
            acc[2][1] = fmaf(p2, v4.y, acc[2][1]);
            acc[2][2] = fmaf(p2, v4.z, acc[2][2]);
            acc[2][3] = fmaf(p2, v4.w, acc[2][3]);
            acc[3][0] = fmaf(p3, v4.x, acc[3][0]);
            acc[3][1] = fmaf(p3, v4.y, acc[3][1]);
            acc[3][2] = fmaf(p3, v4.z, acc[3][2]);
            acc[3][3] = fmaf(p3, v4.w, acc[3][3]);
        }
    }

    // normalize and write ctx in [s][h*64+d] layout (ready for proj GEMM)
    #pragma unroll
    for (int a = 0; a < 4; a++) {
        const float inv = 1.0f / l_i[a];
        float4 o = make_float4(acc[a][0]*inv, acc[a][1]*inv,
                               acc[a][2]*inv, acc[a][3]*inv);
        *(float4*)&ctx[(size_t)(i0 + ty*4 + a) * HID + h * DEP + tx*4] = o;
    }
}

extern "C" void kernel_launch(void* const* d_in, const int* in_sizes, int n_in,
                              void* d_out, int out_size, void* d_ws, size_t ws_size,
                              hipStream_t stream)
{
    (void)in_sizes; (void)n_in; (void)out_size; (void)ws_size;
    const float* x  = (const float*)d_in[0];   // [1,2048,1024]
    const float* Wa = (const float*)d_in[1];   // [1024,3072]
    const float* ba = (const float*)d_in[2];   // [1,3072]
    const float* Wp = (const float*)d_in[3];   // [1024,1024]
    const float* bp = (const float*)d_in[4];   // [1,1024]
    const float* E  = (const float*)d_in[5];   // [16,2048,64]
    float* out = (float*)d_out;                // [1,2048,1024]

    float* qw  = (float*)d_ws;                 // [16][2048][64]
    float* kw  = qw + (size_t)NH * SEQ * DEP;
    float* vw  = kw + (size_t)NH * SEQ * DEP;
    float* ctx = vw + (size_t)NH * SEQ * DEP;  // [2048][1024]

    // qkv = x @ Wa + ba, scattered to split-head q/k/v
    gemm64<<<dim3(48, 32), 256, 0, stream>>>(x, Wa, ba, nullptr,
                                             SEQ, 3*HID, HID, 1, qw, kw, vw);
    // flash attention with relative bias
    attn_flash<<<dim3(SEQ/64, NH), 256, 0, stream>>>(qw, kw, vw, E, ctx);
    // out = ctx @ Wp + bp
    gemm64<<<dim3(16, 32), 256, 0, stream>>>(ctx, Wp, bp, out,
                                             SEQ, HID, HID, 0,
                                             nullptr, nullptr, nullptr);
}

// Round 2
// 246.484 us; speedup vs baseline: 3.3008x; 3.3008x over previous
//
#include <hip/hip_runtime.h>
#include <math.h>

#define SEQ  2048
#define NH   16
#define DEP  64
#define HID  1024

typedef __attribute__((ext_vector_type(8))) short s16x8;
typedef __attribute__((ext_vector_type(4))) float f32x4;

#define MFMA16(a, b, c) __builtin_amdgcn_mfma_f32_16x16x32_bf16(a, b, c, 0, 0, 0)
#define GLDS16(g, l)                                                           \
  __builtin_amdgcn_global_load_lds(                                            \
      (const __attribute__((address_space(1))) void*)(g),                      \
      (__attribute__((address_space(3))) void*)(l), 16, 0, 0)

__device__ __forceinline__ ushort f2b(float f) {
  union { float f; unsigned u; } x; x.f = f;
  unsigned r = (x.u + 0x7fff + ((x.u >> 16) & 1)) >> 16;
  return (ushort)r;
}

// ---------------------------------------------------------------------------
// fp32 -> bf16 elementwise (x, E)
// ---------------------------------------------------------------------------
__global__ __launch_bounds__(256) void cvt_bf16(const float* __restrict__ in,
                                                ushort* __restrict__ out, int n4) {
  int i = blockIdx.x * blockDim.x + threadIdx.x;
  int stride = gridDim.x * blockDim.x;
  for (; i < n4; i += stride) {
    float4 v = *(const float4*)&in[(size_t)i * 4];
    ushort4 o = {f2b(v.x), f2b(v.y), f2b(v.z), f2b(v.w)};
    *(ushort4*)&out[(size_t)i * 4] = o;
  }
}

// ---------------------------------------------------------------------------
// fp32 [R][C] -> bf16 [C][R]  (weight transpose, 64x64 LDS tiles)
// ---------------------------------------------------------------------------
__global__ __launch_bounds__(256) void transpose_w(const float* __restrict__ in,
                                                   ushort* __restrict__ out,
                                                   int R, int C) {
  __shared__ float Ls[64 * 68];
  const int t = threadIdx.x;
  const int k0 = blockIdx.y * 64, n0 = blockIdx.x * 64;
  const int r = t >> 4, c4 = t & 15;
  #pragma unroll
  for (int p = 0; p < 4; p++) {
    float4 v = *(const float4*)&in[(size_t)(k0 + r + 16 * p) * C + n0 + c4 * 4];
    *(float4*)&Ls[(r + 16 * p) * 68 + c4 * 4] = v;
  }
  __syncthreads();
  #pragma unroll
  for (int p = 0; p < 4; p++) {
    int rw = r + 16 * p;
    ushort4 o;
    o.x = f2b(Ls[(c4 * 4 + 0) * 68 + rw]);
    o.y = f2b(Ls[(c4 * 4 + 1) * 68 + rw]);
    o.z = f2b(Ls[(c4 * 4 + 2) * 68 + rw]);
    o.w = f2b(Ls[(c4 * 4 + 3) * 68 + rw]);
    *(ushort4*)&out[(size_t)(n0 + rw) * R + k0 + c4 * 4] = o;
  }
}

// ---------------------------------------------------------------------------
// bf16 v [16][2048][64] -> vT [16][64][2048]
// ---------------------------------------------------------------------------
__global__ __launch_bounds__(256) void transpose_v(const ushort* __restrict__ v,
                                                   ushort* __restrict__ vt) {
  __shared__ ushort T[64 * 72];
  const int t = threadIdx.x, h = blockIdx.y, s0 = blockIdx.x * 64;
  #pragma unroll
  for (int j = 0; j < 2; j++) {
    int c = t + 256 * j, r = c >> 3, c8 = c & 7;
    *(int4*)((char*)T + r * 144 + c8 * 16) =
        *(const int4*)&v[((size_t)h * SEQ + s0 + r) * 64 + c8 * 8];
  }
  __syncthreads();
  #pragma unroll
  for (int j = 0; j < 2; j++) {
    int c = t + 256 * j, d = c >> 3, c8 = c & 7;
    ushort tmp[8];
    #pragma unroll
    for (int jj = 0; jj < 8; jj++) tmp[jj] = T[(c8 * 8 + jj) * 72 + d];
    *(int4*)&vt[((size_t)h * 64 + d) * SEQ + s0 + c8 * 8] = *(int4*)tmp;
  }
}

// ---------------------------------------------------------------------------
// bf16 MFMA GEMM: D[M][N] = A[M][K] @ Bt[N][K]^T + bias
// 128x128 tile, BK=32, global_load_lds(16B) staging, XOR chunk swizzle.
// mode 0: scatter to q(*0.125)/k/v bf16 split-head [h][s][d]
// mode 1: fp32 output Cout[M][N]
// ---------------------------------------------------------------------------
__global__ __launch_bounds__(256) void gemm_mfma(
    const ushort* __restrict__ A, const ushort* __restrict__ Bt,
    const float* __restrict__ bias, int M, int N, int K, int mode,
    ushort* __restrict__ qd, ushort* __restrict__ kd, ushort* __restrict__ vd,
    float* __restrict__ Cout) {
  (void)M;
  __shared__ ushort As[128 * 32];   // 64 B rows, chunk slot = q ^ ((row>>2)&3)
  __shared__ ushort Bs[128 * 32];
  const int t = threadIdx.x, l = t & 63, w = t >> 6;
  const int lr = l & 15, quad = l >> 4;
  const int m0 = blockIdx.y * 128, n0 = blockIdx.x * 128;
  const int wr = (w >> 1) * 64, wc = (w & 1) * 64;
  f32x4 acc[4][4] = {};
  // staging: lane l fetches logical chunk q so the fixed LDS slot is swizzled
  const int qch = (l & 3) ^ ((l >> 4) & 3);
  const int srow = 32 * w + (l >> 2);
  const ushort* gA = A + (size_t)(m0 + srow) * K + qch * 8;
  const ushort* gB = Bt + (size_t)(n0 + srow) * K + qch * 8;
  char* ldsA0 = (char*)As + (32 * w) * 64;
  char* ldsB0 = (char*)Bs + (32 * w) * 64;
  const int slot = (quad ^ ((l >> 2) & 3)) * 16;  // byte offset of swizzled chunk

  for (int k0 = 0; k0 < K; k0 += 32) {
    __syncthreads();
    GLDS16(gA + k0, ldsA0);
    GLDS16(gA + k0 + 16 * K, ldsA0 + 1024);
    GLDS16(gB + k0, ldsB0);
    GLDS16(gB + k0 + 16 * K, ldsB0 + 1024);
    __syncthreads();
    s16x8 af[4], bf[4];
    #pragma unroll
    for (int i = 0; i < 4; i++)
      af[i] = *(const s16x8*)((char*)As + (wr + 16 * i + lr) * 64 + slot);
    #pragma unroll
    for (int j = 0; j < 4; j++)
      bf[j] = *(const s16x8*)((char*)Bs + (wc + 16 * j + lr) * 64 + slot);
    #pragma unroll
    for (int i = 0; i < 4; i++)
      #pragma unroll
      for (int j = 0; j < 4; j++)
        acc[i][j] = MFMA16(af[i], bf[j], acc[i][j]);
  }

  #pragma unroll
  for (int i = 0; i < 4; i++) {
    #pragma unroll
    for (int j = 0; j < 4; j++) {
      const int colg = n0 + wc + 16 * j + lr;
      const float bb = bias[colg];
      #pragma unroll
      for (int r = 0; r < 4; r++) {
        const int rowg = m0 + wr + 16 * i + 4 * quad + r;
        float v = acc[i][j][r] + bb;
        if (mode == 0) {
          const int part = colg >> 10, hh = (colg >> 6) & 15, d = colg & 63;
          if (part == 0) v *= 0.125f;  // fold 1/sqrt(64) into q (scales rel too)
          ushort* dst = part == 0 ? qd : (part == 1 ? kd : vd);
          dst[((size_t)hh * SEQ + rowg) * 64 + d] = f2b(v);
        } else {
          Cout[(size_t)rowg * N + colg] = v;
        }
      }
    }
  }
}

// ---------------------------------------------------------------------------
// MFMA flash attention with Transformer-XL relative bias.
// rel[i,j] = q_i . E[2047-(i-j)] (skew identity); per 16x16 subtile only a
// 31-row E band is needed: Rsub = q @ Eband^T by MFMA, then the skew gather
// is a pure cross-lane __shfl (src = (u&15)|(l&48), same reg). Scale is
// pre-folded into q; masked entries = exactly -10000 (exp underflows to 0).
// Block = (head, 64 q-rows), 4 waves; wave w owns q rows [16w,16w+16).
// LDS 45 KB: KT/EB/VS tiles + per-wave P buffer (overlaid with Q staging).
// ---------------------------------------------------------------------------
__global__ __launch_bounds__(256) void attn_mfma(
    const ushort* __restrict__ qw, const ushort* __restrict__ kw,
    const ushort* __restrict__ vT, const ushort* __restrict__ Ebf,
    ushort* __restrict__ ctx) {
  __shared__ ushort KT[64 * 72];    // K tile [j][d]
  __shared__ ushort EB[128 * 72];   // E band [u][d]
  __shared__ ushort VS[64 * 72];    // V^T tile [d][tj]
  __shared__ ushort PQ[64 * 72];    // Q staging, then per-wave P [ti][tj]
  const int t = threadIdx.x, l = t & 63, w = t >> 6;
  const int lr = l & 15, quad = l >> 4;
  const int h = blockIdx.y;
  const int i0 = (31 - (int)blockIdx.x) * 64;  // longest blocks dispatch first

  // per-wave: stage own 16 Q rows, load persistent A-frags (reg-resident)
  {
    const ushort* qg = qw + ((size_t)h * SEQ + i0 + 16 * w) * 64;
    #pragma unroll
    for (int j = 0; j < 2; j++) {
      int c = l * 2 + j, r = c >> 3, c8 = c & 7;
      *(int4*)((char*)PQ + (16 * w + r) * 144 + c8 * 16) =
          *(const int4*)(qg + r * 64 + c8 * 8);
    }
  }
  const s16x8 aq0 = *(const s16x8*)((char*)PQ + (16 * w + lr) * 144 + quad * 16);
  const s16x8 aq1 = *(const s16x8*)((char*)PQ + (16 * w + lr) * 144 + 64 + quad * 16);

  f32x4 o[4] = {};
  float mi[4] = {-INFINITY, -INFINITY, -INFINITY, -INFINITY};
  float li[4] = {0.f, 0.f, 0.f, 0.f};
  const int nkt = i0 / 64 + 1;

  for (int kt = 0; kt < nkt; kt++) {
    const int j0 = kt * 64;
    const int m0 = 1984 - i0 + j0;  // E band start (global row)
    __syncthreads();
    {
      const ushort* kg = kw + ((size_t)h * SEQ + j0) * 64;
      const ushort* vg = vT + (size_t)h * 64 * SEQ + j0;
      const ushort* eg = Ebf + (size_t)h * SEQ * 64;
      #pragma unroll
      for (int j = 0; j < 2; j++) {
        int c = t + 256 * j, r = c >> 3, c8 = c & 7;
        *(int4*)((char*)KT + r * 144 + c8 * 16) = *(const int4*)(kg + r * 64 + c8 * 8);
        *(int4*)((char*)VS + r * 144 + c8 * 16) =
            *(const int4*)(vg + (size_t)r * SEQ + c8 * 8);
      }
      #pragma unroll
      for (int j = 0; j < 4; j++) {
        int c = t + 256 * j, r = c >> 3, c8 = c & 7;
        int g = m0 + r; if (g > SEQ - 1) g = SEQ - 1;  // OOB rows only feed masked entries
        *(int4*)((char*)EB + r * 144 + c8 * 16) = *(const int4*)(eg + (size_t)g * 64 + c8 * 8);
      }
    }
    __syncthreads();

    // S = q @ k^T
    f32x4 s[4];
    #pragma unroll
    for (int b = 0; b < 4; b++) {
      s16x8 bk0 = *(const s16x8*)((char*)KT + (16 * b + lr) * 144 + quad * 16);
      s16x8 bk1 = *(const s16x8*)((char*)KT + (16 * b + lr) * 144 + 64 + quad * 16);
      f32x4 z = {};
      z = MFMA16(aq0, bk0, z);
      z = MFMA16(aq1, bk1, z);
      s[b] = z;
    }

    // relative bias: Rsub tiles + shfl skew gather (E tiles shared across b)
    {
      const int ebase = 48 - 16 * w;
      s16x8 ca0 = *(const s16x8*)((char*)EB + (ebase + lr) * 144 + quad * 16);
      s16x8 ca1 = *(const s16x8*)((char*)EB + (ebase + lr) * 144 + 64 + quad * 16);
      #pragma unroll
      for (int b = 0; b < 4; b++) {
        s16x8 cb0 = *(const s16x8*)((char*)EB + (ebase + 16 * (b + 1) + lr) * 144 + quad * 16);
        s16x8 cb1 = *(const s16x8*)((char*)EB + (ebase + 16 * (b + 1) + lr) * 144 + 64 + quad * 16);
        f32x4 r0 = {}, r1 = {};
        r0 = MFMA16(aq0, ca0, r0);
        r0 = MFMA16(aq1, ca1, r0);
        r1 = MFMA16(aq0, cb0, r1);
        r1 = MFMA16(aq1, cb1, r1);
        #pragma unroll
        for (int r = 0; r < 4; r++) {
          int ti = 4 * quad + r;
          int u = lr - ti + 15;              // 0..30
          int src = (u & 15) | (l & 48);
          float v0 = __shfl(r0[r], src);
          float v1 = __shfl(r1[r], src);
          s[b][r] += (u < 16) ? v0 : v1;
        }
        ca0 = cb0; ca1 = cb1;
      }
    }

    // causal mask (diagonal tile only; scale already folded into q)
    if (kt == nkt - 1) {
      #pragma unroll
      for (int b = 0; b < 4; b++)
        #pragma unroll
        for (int r = 0; r < 4; r++) {
          int ii = 16 * w + 4 * quad + r;
          if (16 * b + lr > ii) s[b][r] = -10000.0f;
        }
    }

    // online softmax (row = 16-lane group, 4 rows per quad via reg idx)
    #pragma unroll
    for (int r = 0; r < 4; r++) {
      float mx = fmaxf(fmaxf(s[0][r], s[1][r]), fmaxf(s[2][r], s[3][r]));
      mx = fmaxf(mx, __shfl_xor(mx, 1));
      mx = fmaxf(mx, __shfl_xor(mx, 2));
      mx = fmaxf(mx, __shfl_xor(mx, 4));
      mx = fmaxf(mx, __shfl_xor(mx, 8));
      float mnew = fmaxf(mi[r], mx);
      float al = __expf(mi[r] - mnew);  // first tile: exp(-inf)=0
      mi[r] = mnew;
      float ps = 0.f;
      #pragma unroll
      for (int b = 0; b < 4; b++) {
        float p = __expf(s[b][r] - mnew);
        s[b][r] = p; ps += p;
      }
      ps += __shfl_xor(ps, 1);
      ps += __shfl_xor(ps, 2);
      ps += __shfl_xor(ps, 4);
      ps += __shfl_xor(ps, 8);
      li[r] = li[r] * al + ps;
      #pragma unroll
      for (int dc = 0; dc < 4; dc++) o[dc][r] *= al;
    }

    // P: C-layout regs -> per-wave LDS (bf16) -> A-layout frags
    char* Pw = (char*)PQ + 16 * w * 144;
    #pragma unroll
    for (int b = 0; b < 4; b++)
      #pragma unroll
      for (int r = 0; r < 4; r++)
        *(ushort*)(Pw + (4 * quad + r) * 144 + (16 * b + lr) * 2) = f2b(s[b][r]);
    s16x8 pa0 = *(const s16x8*)(Pw + lr * 144 + quad * 16);
    s16x8 pa1 = *(const s16x8*)(Pw + lr * 144 + 64 + quad * 16);
    #pragma unroll
    for (int dc = 0; dc < 4; dc++) {
      s16x8 bv0 = *(const s16x8*)((char*)VS + (16 * dc + lr) * 144 + quad * 16);
      s16x8 bv1 = *(const s16x8*)((char*)VS + (16 * dc + lr) * 144 + 64 + quad * 16);
      o[dc] = MFMA16(pa0, bv0, o[dc]);
      o[dc] = MFMA16(pa1, bv1, o[dc]);
    }
  }

  // normalize, write ctx bf16 in [s][h*64+d] layout (proj GEMM A-operand)
  #pragma unroll
  for (int r = 0; r < 4; r++) {
    float inv = 1.0f / li[r];
    #pragma unroll
    for (int dc = 0; dc < 4; dc++) {
      int row = i0 + 16 * w + 4 * quad + r;
      int col = h * 64 + 16 * dc + lr;
      ctx[(size_t)row * HID + col] = f2b(o[dc][r] * inv);
    }
  }
}

extern "C" void kernel_launch(void* const* d_in, const int* in_sizes, int n_in,
                              void* d_out, int out_size, void* d_ws, size_t ws_size,
                              hipStream_t stream) {
  (void)in_sizes; (void)n_in; (void)out_size; (void)ws_size;
  const float* x  = (const float*)d_in[0];   // [1,2048,1024]
  const float* Wa = (const float*)d_in[1];   // [1024,3072]
  const float* ba = (const float*)d_in[2];   // [3072]
  const float* Wp = (const float*)d_in[3];   // [1024,1024]
  const float* bp = (const float*)d_in[4];   // [1024]
  const float* E  = (const float*)d_in[5];   // [16,2048,64]
  float* out = (float*)d_out;                // [1,2048,1024]

  ushort* xb  = (ushort*)d_ws;               // 2M ush (4 MB); reused as ctx
  ushort* ctx = xb;                          // safe: attention runs after qkv GEMM
  ushort* Wat = xb + (size_t)2 * 1024 * 1024;   // 3M ush
  ushort* Wpt = Wat + (size_t)3 * 1024 * 1024;  // 1M ush
  ushort* Ebf = Wpt + (size_t)1024 * 1024;      // 2M ush
  ushort* qwp = Ebf + (size_t)2 * 1024 * 1024;
  ushort* kwp = qwp + (size_t)2 * 1024 * 1024;
  ushort* vwp = kwp + (size_t)2 * 1024 * 1024;
  ushort* vTp = vwp + (size_t)2 * 1024 * 1024;  // total 32 MB

  cvt_bf16<<<1024, 256, 0, stream>>>(x, xb, SEQ * HID / 4);
  cvt_bf16<<<1024, 256, 0, stream>>>(E, Ebf, NH * SEQ * DEP / 4);
  transpose_w<<<dim3(48, 16), 256, 0, stream>>>(Wa, Wat, HID, 3 * HID);
  transpose_w<<<dim3(16, 16), 256, 0, stream>>>(Wp, Wpt, HID, HID);

  gemm_mfma<<<dim3(24, 16), 256, 0, stream>>>(xb, Wat, ba, SEQ, 3 * HID, HID, 0,
                                              qwp, kwp, vwp, nullptr);
  transpose_v<<<dim3(32, 16), 256, 0, stream>>>(vwp, vTp);
  attn_mfma<<<dim3(32, 16), 256, 0, stream>>>(qwp, kwp, vTp, Ebf, ctx);
  gemm_mfma<<<dim3(8, 16), 256, 0, stream>>>(ctx, Wpt, bp, SEQ, HID, HID, 1,
                                             nullptr, nullptr, nullptr, out);
}